// Round 9
// baseline (487.398 us; speedup 1.0000x reference)
//
#include <hip/hip_runtime.h>
#include <hip/hip_fp16.h>

#define N_NODES 50000
#define N_EDGES 800000
#define NODE_DIM 128
#define C 64
#define N_GRAPHS 512
#define N_LAYERS 5
#define BN_EPS 1e-5f

#define SCAN_BLOCKS 196   // ceil(50000/256)
#define NBUCK 196         // buckets of 256 nodes: bucket = dst >> 8
#define ECHUNK 4096       // edges per block in CSR-build passes

typedef unsigned int u32;
typedef unsigned short u16;

// fp16 helpers: 2 ch per u32 word
__device__ inline float2 h2f(u32 v) {
    __half2 h; __builtin_memcpy(&h, &v, 4);
    return __half22float2(h);
}
__device__ inline u32 f2h2(float a, float b) {
    __half2 h = __floats2half2_rn(a, b);
    u32 v; __builtin_memcpy(&v, &h, 4);
    return v;
}

// =============================================================
// encoder: z = x @ enc_W + enc_b   [50000,128]x[128,64], z stored fp16
// =============================================================
__global__ __launch_bounds__(256) void enc_kernel(const float* __restrict__ x,
                                                  const float* __restrict__ W,
                                                  const float* __restrict__ b,
                                                  u32* __restrict__ z) {
    __shared__ float As[64 * 132];        // [k][row], row-dim padded
    __shared__ float Ws[NODE_DIM * C];    // 32 KB, full K
    int t = threadIdx.x;
    int tc = t & 15, tr = t >> 4;
    for (int i = t; i < NODE_DIM * C; i += 256) Ws[i] = W[i];
    int row0 = blockIdx.x * 128;
    float4 bv = ((const float4*)b)[tc];
    float acc[8][4];
#pragma unroll
    for (int i = 0; i < 8; ++i) { acc[i][0] = bv.x; acc[i][1] = bv.y; acc[i][2] = bv.z; acc[i][3] = bv.w; }

    for (int kc = 0; kc < 2; ++kc) {
        __syncthreads();
        for (int it = 0; it < 8; ++it) {
            int idx = t + 256 * it;
            int r = idx >> 4, f4 = idx & 15;
            int grow = row0 + r;
            float4 v = (grow < N_NODES) ? ((const float4*)x)[grow * 32 + kc * 16 + f4]
                                        : make_float4(0.f, 0.f, 0.f, 0.f);
            int k4 = f4 * 4;
            As[(k4 + 0) * 132 + r] = v.x;
            As[(k4 + 1) * 132 + r] = v.y;
            As[(k4 + 2) * 132 + r] = v.z;
            As[(k4 + 3) * 132 + r] = v.w;
        }
        __syncthreads();
#pragma unroll 4
        for (int k = 0; k < 64; ++k) {
            const float* ap = As + k * 132 + tr * 8;
            float4 a0 = *(const float4*)(ap);
            float4 a1 = *(const float4*)(ap + 4);
            float4 w = *(const float4*)(Ws + (kc * 64 + k) * C + tc * 4);
            float av[8] = {a0.x, a0.y, a0.z, a0.w, a1.x, a1.y, a1.z, a1.w};
#pragma unroll
            for (int i = 0; i < 8; ++i) {
                acc[i][0] = fmaf(av[i], w.x, acc[i][0]);
                acc[i][1] = fmaf(av[i], w.y, acc[i][1]);
                acc[i][2] = fmaf(av[i], w.z, acc[i][2]);
                acc[i][3] = fmaf(av[i], w.w, acc[i][3]);
            }
        }
    }
#pragma unroll
    for (int i = 0; i < 8; ++i) {
        int grow = row0 + tr * 8 + i;
        if (grow < N_NODES) {
            uint2 o;
            o.x = f2h2(acc[i][0], acc[i][1]);
            o.y = f2h2(acc[i][2], acc[i][3]);
            ((uint2*)z)[grow * 16 + tc] = o;
        }
    }
}

// ================= bucketed CSR build =================
__global__ __launch_bounds__(256) void csr_hist(const int* __restrict__ ei,
                                                int* __restrict__ bcount) {
    __shared__ int lhist[NBUCK];
    int t = threadIdx.x;
    if (t < NBUCK) lhist[t] = 0;
    __syncthreads();
    int e0 = blockIdx.x * ECHUNK;
    int e1 = min(e0 + ECHUNK, N_EDGES);
    for (int e = e0 + t; e < e1; e += 256)
        atomicAdd(&lhist[ei[N_EDGES + e] >> 8], 1);
    __syncthreads();
    if (t < NBUCK && lhist[t] > 0) atomicAdd(&bcount[t], lhist[t]);
}

__global__ __launch_bounds__(256) void csr_bscan(const int* __restrict__ bcount,
                                                 int* __restrict__ bbase,
                                                 int* __restrict__ bcursor,
                                                 int* __restrict__ offs) {
    __shared__ int s[256];
    int t = threadIdx.x;
    int v = (t < NBUCK) ? bcount[t] : 0;
    s[t] = v;
    for (int off = 1; off < 256; off <<= 1) {
        __syncthreads();
        int x = (t >= off) ? s[t - off] : 0;
        __syncthreads();
        s[t] += x;
    }
    __syncthreads();
    if (t < NBUCK) {
        bbase[t + 1] = s[t];
        bcursor[t] = s[t] - v;   // exclusive base = cursor seed
    }
    if (t == 0) { bbase[0] = 0; offs[N_NODES] = N_EDGES; }
}

// A2: stage entries bucket-major; entry = src | (dstLow8 << 16)
__global__ __launch_bounds__(256) void csr_stage(const int* __restrict__ ei,
                                                 int* __restrict__ bcursor,
                                                 u32* __restrict__ staged) {
    __shared__ int lhist[NBUCK];
    __shared__ int lbase[NBUCK];
    __shared__ int lcur[NBUCK];
    int t = threadIdx.x;
    if (t < NBUCK) lhist[t] = 0;
    __syncthreads();
    int e0 = blockIdx.x * ECHUNK;
    int e1 = min(e0 + ECHUNK, N_EDGES);
    for (int e = e0 + t; e < e1; e += 256)
        atomicAdd(&lhist[ei[N_EDGES + e] >> 8], 1);
    __syncthreads();
    if (t < NBUCK) {
        int c = lhist[t];
        lbase[t] = (c > 0) ? atomicAdd(&bcursor[t], c) : 0;
        lcur[t] = 0;
    }
    __syncthreads();
    for (int e = e0 + t; e < e1; e += 256) {
        int src = ei[e];
        int dst = ei[N_EDGES + e];
        int bk = dst >> 8;
        int r = atomicAdd(&lcur[bk], 1);
        staged[lbase[bk] + r] = (u32)src | ((u32)(dst & 255) << 16);
    }
}

// B: per-bucket counting sort -> csr (u16) + per-node offs
__global__ __launch_bounds__(256) void csr_finalize(const u32* __restrict__ staged,
                                                    const int* __restrict__ bbase,
                                                    u16* __restrict__ csr,
                                                    int* __restrict__ offs) {
    __shared__ int lhist[256];
    __shared__ int lexc[256];
    __shared__ int lcur[256];
    int t = threadIdx.x;
    int b = blockIdx.x;
    int sbeg = bbase[b], send = bbase[b + 1];
    lhist[t] = 0;
    __syncthreads();
    for (int i = sbeg + t; i < send; i += 256)
        atomicAdd(&lhist[(staged[i] >> 16) & 255], 1);
    __syncthreads();
    int v = lhist[t];
    lexc[t] = v;
    for (int off = 1; off < 256; off <<= 1) {
        __syncthreads();
        int x = (t >= off) ? lexc[t - off] : 0;
        __syncthreads();
        lexc[t] += x;
    }
    __syncthreads();
    int excl = lexc[t] - v;
    int node = b * 256 + t;
    if (node < N_NODES) offs[node] = sbeg + excl;
    lcur[t] = excl;
    __syncthreads();
    for (int i = sbeg + t; i < send; i += 256) {
        u32 ent = staged[i];
        int dlow = (ent >> 16) & 255;
        int r = atomicAdd(&lcur[dlow], 1);
        csr[sbeg + r] = (u16)(ent & 0xFFFFu);
    }
}

// ---------------- graph start offsets from sorted batch ----------------
__global__ __launch_bounds__(256) void gstart_kernel(const int* __restrict__ batch,
                                                     int* __restrict__ goffs) {
    int n = blockIdx.x * 256 + threadIdx.x;
    if (n >= N_NODES) return;
    if (n == 0) {
        for (int g = 0; g <= batch[0]; ++g) goffs[g] = 0;
    } else {
        int bp = batch[n - 1], bc = batch[n];
        for (int g = bp + 1; g <= bc; ++g) goffs[g] = n;
    }
    if (n == N_NODES - 1) {
        for (int g = batch[n] + 1; g <= N_GRAPHS; ++g) goffs[g] = N_NODES;
    }
}

// =============================================================
// fused gather(fp16) + BN-apply + MLP + BN stats, BM=32.
// 1563 blocks (~6/CU), LDS 20.6 KB. Each thread gathers exactly ONE node
// (8 lanes/row x uint4); GEMMs are TM=2 x TN=4 over 32 rows.
// Asw: u32 [32 words][36 rows] fp16x2, word w = channels {2w,2w+1}.
// =============================================================
__global__ __launch_bounds__(256) void mlp_gather_kernel(const u16* __restrict__ csr_src,
                                                         const int* __restrict__ offs,
                                                         const u32* __restrict__ z_in,
                                                         const float* __restrict__ ss,
                                                         int use_ss,
                                                         u32* __restrict__ z_out,
                                                         const float* __restrict__ W1,
                                                         const float* __restrict__ b1,
                                                         const float* __restrict__ W2,
                                                         const float* __restrict__ b2,
                                                         float* __restrict__ stats) {
    __shared__ u32 Asw[32 * 36];     // 4.6 KB, fp16-packed [word][row(+pad)]
    __shared__ float Ws[C * C];      // 16 KB: W1, then W2, then stats-reduce
    int t = threadIdx.x;
    int tc = t & 15, tr = t >> 4;
    for (int i = t; i < C * C; i += 256) Ws[i] = W1[i];
    int row0 = blockIdx.x * 32;

    // ---- gather one node per thread: 8 lanes/row, uint4 = 8 fp16 ch ----
    int tg = t & 7;         // channel-group: ch tg*8 .. +7
    int rg = t >> 3;        // row 0..31
    {
        float scv[8], shv[8];
        if (use_ss) {
            float4 s0 = ((const float4*)ss)[tg * 2], s1 = ((const float4*)ss)[tg * 2 + 1];
            float4 h0 = ((const float4*)(ss + C))[tg * 2], h1 = ((const float4*)(ss + C))[tg * 2 + 1];
            scv[0] = s0.x; scv[1] = s0.y; scv[2] = s0.z; scv[3] = s0.w;
            scv[4] = s1.x; scv[5] = s1.y; scv[6] = s1.z; scv[7] = s1.w;
            shv[0] = h0.x; shv[1] = h0.y; shv[2] = h0.z; shv[3] = h0.w;
            shv[4] = h1.x; shv[5] = h1.y; shv[6] = h1.z; shv[7] = h1.w;
        } else {
#pragma unroll
            for (int i = 0; i < 8; ++i) { scv[i] = 1.f; shv[i] = 0.f; }
        }
        const uint4* z4 = (const uint4*)z_in;
        int node = row0 + rg;
        float acc[8] = {0.f, 0.f, 0.f, 0.f, 0.f, 0.f, 0.f, 0.f};
        if (node < N_NODES) {
            uint4 sv = z4[node * 8 + tg];   // self term (GIN eps=0)
            float2 p0 = h2f(sv.x), p1 = h2f(sv.y), p2 = h2f(sv.z), p3 = h2f(sv.w);
            acc[0] = p0.x; acc[1] = p0.y; acc[2] = p1.x; acc[3] = p1.y;
            acc[4] = p2.x; acc[5] = p2.y; acc[6] = p3.x; acc[7] = p3.y;
            int beg = offs[node], end = offs[node + 1];
            int e = beg;
            for (; e + 3 < end; e += 4) {   // 4 independent 16B line-loads in flight
                int s0 = csr_src[e], s1 = csr_src[e + 1], s2 = csr_src[e + 2], s3 = csr_src[e + 3];
                uint4 v0 = z4[s0 * 8 + tg], v1 = z4[s1 * 8 + tg];
                uint4 v2 = z4[s2 * 8 + tg], v3 = z4[s3 * 8 + tg];
                float2 a0 = h2f(v0.x), a1 = h2f(v1.x), a2 = h2f(v2.x), a3 = h2f(v3.x);
                acc[0] += (a0.x + a1.x) + (a2.x + a3.x);
                acc[1] += (a0.y + a1.y) + (a2.y + a3.y);
                a0 = h2f(v0.y); a1 = h2f(v1.y); a2 = h2f(v2.y); a3 = h2f(v3.y);
                acc[2] += (a0.x + a1.x) + (a2.x + a3.x);
                acc[3] += (a0.y + a1.y) + (a2.y + a3.y);
                a0 = h2f(v0.z); a1 = h2f(v1.z); a2 = h2f(v2.z); a3 = h2f(v3.z);
                acc[4] += (a0.x + a1.x) + (a2.x + a3.x);
                acc[5] += (a0.y + a1.y) + (a2.y + a3.y);
                a0 = h2f(v0.w); a1 = h2f(v1.w); a2 = h2f(v2.w); a3 = h2f(v3.w);
                acc[6] += (a0.x + a1.x) + (a2.x + a3.x);
                acc[7] += (a0.y + a1.y) + (a2.y + a3.y);
            }
            for (; e < end; ++e) {
                uint4 v = z4[csr_src[e] * 8 + tg];
                float2 a0 = h2f(v.x), a1 = h2f(v.y), a2 = h2f(v.z), a3 = h2f(v.w);
                acc[0] += a0.x; acc[1] += a0.y; acc[2] += a1.x; acc[3] += a1.y;
                acc[4] += a2.x; acc[5] += a2.y; acc[6] += a3.x; acc[7] += a3.y;
            }
            float cnt = (float)(end - beg + 1);
#pragma unroll
            for (int i = 0; i < 8; ++i) acc[i] = fmaf(acc[i], scv[i], cnt * shv[i]);
        }
        Asw[(tg * 4 + 0) * 36 + rg] = f2h2(acc[0], acc[1]);
        Asw[(tg * 4 + 1) * 36 + rg] = f2h2(acc[2], acc[3]);
        Asw[(tg * 4 + 2) * 36 + rg] = f2h2(acc[4], acc[5]);
        Asw[(tg * 4 + 3) * 36 + rg] = f2h2(acc[6], acc[7]);
    }
    __syncthreads();

    // ---- GEMM1: t1 = relu(y@W1+b1), TM=2 x TN=4 ----
    float4 b1v = ((const float4*)b1)[tc];
    float a[2][4];
#pragma unroll
    for (int i = 0; i < 2; ++i) { a[i][0] = b1v.x; a[i][1] = b1v.y; a[i][2] = b1v.z; a[i][3] = b1v.w; }
#pragma unroll 4
    for (int w = 0; w < 32; ++w) {
        uint2 aw = *(const uint2*)(Asw + w * 36 + tr * 2);  // rows tr*2,tr*2+1; ch {2w,2w+1}
        float2 r0 = h2f(aw.x), r1 = h2f(aw.y);
        float4 w0 = *(const float4*)(Ws + (2 * w) * C + tc * 4);
        float4 w1 = *(const float4*)(Ws + (2 * w + 1) * C + tc * 4);
        a[0][0] = fmaf(r0.x, w0.x, a[0][0]); a[0][0] = fmaf(r0.y, w1.x, a[0][0]);
        a[0][1] = fmaf(r0.x, w0.y, a[0][1]); a[0][1] = fmaf(r0.y, w1.y, a[0][1]);
        a[0][2] = fmaf(r0.x, w0.z, a[0][2]); a[0][2] = fmaf(r0.y, w1.z, a[0][2]);
        a[0][3] = fmaf(r0.x, w0.w, a[0][3]); a[0][3] = fmaf(r0.y, w1.w, a[0][3]);
        a[1][0] = fmaf(r1.x, w0.x, a[1][0]); a[1][0] = fmaf(r1.y, w1.x, a[1][0]);
        a[1][1] = fmaf(r1.x, w0.y, a[1][1]); a[1][1] = fmaf(r1.y, w1.y, a[1][1]);
        a[1][2] = fmaf(r1.x, w0.z, a[1][2]); a[1][2] = fmaf(r1.y, w1.z, a[1][2]);
        a[1][3] = fmaf(r1.x, w0.w, a[1][3]); a[1][3] = fmaf(r1.y, w1.w, a[1][3]);
    }
    __syncthreads();  // Asw + Ws(W1) reads done

    // ---- restage t1^T (fp16) into Asw; load W2 ----
    {
        uint2 q0, q1;
        q0.x = f2h2(fmaxf(a[0][0], 0.f), fmaxf(a[0][1], 0.f));  // row tr*2,   ch pair tc*2
        q0.y = f2h2(fmaxf(a[1][0], 0.f), fmaxf(a[1][1], 0.f));  // row tr*2+1, ch pair tc*2
        q1.x = f2h2(fmaxf(a[0][2], 0.f), fmaxf(a[0][3], 0.f));  // row tr*2,   ch pair tc*2+1
        q1.y = f2h2(fmaxf(a[1][2], 0.f), fmaxf(a[1][3], 0.f));
        *(uint2*)(Asw + (tc * 2) * 36 + tr * 2) = q0;
        *(uint2*)(Asw + (tc * 2 + 1) * 36 + tr * 2) = q1;
    }
    for (int i = t; i < C * C; i += 256) Ws[i] = W2[i];
    __syncthreads();

    // ---- GEMM2: z = relu(t1@W2+b2) ----
    float4 b2v = ((const float4*)b2)[tc];
#pragma unroll
    for (int i = 0; i < 2; ++i) { a[i][0] = b2v.x; a[i][1] = b2v.y; a[i][2] = b2v.z; a[i][3] = b2v.w; }
#pragma unroll 4
    for (int w = 0; w < 32; ++w) {
        uint2 aw = *(const uint2*)(Asw + w * 36 + tr * 2);
        float2 r0 = h2f(aw.x), r1 = h2f(aw.y);
        float4 w0 = *(const float4*)(Ws + (2 * w) * C + tc * 4);
        float4 w1 = *(const float4*)(Ws + (2 * w + 1) * C + tc * 4);
        a[0][0] = fmaf(r0.x, w0.x, a[0][0]); a[0][0] = fmaf(r0.y, w1.x, a[0][0]);
        a[0][1] = fmaf(r0.x, w0.y, a[0][1]); a[0][1] = fmaf(r0.y, w1.y, a[0][1]);
        a[0][2] = fmaf(r0.x, w0.z, a[0][2]); a[0][2] = fmaf(r0.y, w1.z, a[0][2]);
        a[0][3] = fmaf(r0.x, w0.w, a[0][3]); a[0][3] = fmaf(r0.y, w1.w, a[0][3]);
        a[1][0] = fmaf(r1.x, w0.x, a[1][0]); a[1][0] = fmaf(r1.y, w1.x, a[1][0]);
        a[1][1] = fmaf(r1.x, w0.y, a[1][1]); a[1][1] = fmaf(r1.y, w1.y, a[1][1]);
        a[1][2] = fmaf(r1.x, w0.z, a[1][2]); a[1][2] = fmaf(r1.y, w1.z, a[1][2]);
        a[1][3] = fmaf(r1.x, w0.w, a[1][3]); a[1][3] = fmaf(r1.y, w1.w, a[1][3]);
    }

    // ---- relu, fp16 store, local BN stats (fp32) ----
    float lsum[4] = {0.f, 0.f, 0.f, 0.f};
    float lsq[4] = {0.f, 0.f, 0.f, 0.f};
#pragma unroll
    for (int i = 0; i < 2; ++i) {
        int grow = row0 + tr * 2 + i;
        if (grow < N_NODES) {
            float o0 = fmaxf(a[i][0], 0.f), o1 = fmaxf(a[i][1], 0.f);
            float o2 = fmaxf(a[i][2], 0.f), o3 = fmaxf(a[i][3], 0.f);
            uint2 o;
            o.x = f2h2(o0, o1);
            o.y = f2h2(o2, o3);
            ((uint2*)z_out)[grow * 16 + tc] = o;
            lsum[0] += o0; lsum[1] += o1; lsum[2] += o2; lsum[3] += o3;
            lsq[0] += o0 * o0; lsq[1] += o1 * o1; lsq[2] += o2 * o2; lsq[3] += o3 * o3;
        }
    }
    __syncthreads();  // Ws(W2) reads done; reuse as reduction buffer 16x128
    float* red = Ws;
#pragma unroll
    for (int j = 0; j < 4; ++j) {
        red[tr * 128 + tc * 4 + j] = lsum[j];
        red[tr * 128 + 64 + tc * 4 + j] = lsq[j];
    }
    __syncthreads();
    if (t < 128) {
        float s = 0.f;
#pragma unroll
        for (int r = 0; r < 16; ++r) s += red[r * 128 + t];
        atomicAdd(&stats[t], s);  // [0..63]=sum, [64..127]=sumsq
    }
}

// ---------------- BN finalize ----------------
__global__ void bn_finalize(const float* __restrict__ stats,
                            const float* __restrict__ gamma,
                            const float* __restrict__ beta,
                            float* __restrict__ ss) {
    int c = threadIdx.x;
    if (c >= C) return;
    const float invN = 1.0f / (float)N_NODES;
    float mean = stats[c] * invN;
    float var = stats[C + c] * invN - mean * mean;
    float rstd = rsqrtf(var + BN_EPS);
    float sc = gamma[c] * rstd;
    ss[c] = sc;
    ss[C + c] = beta[c] - mean * sc;
}

// ---------------- pool: segmented reduction over sorted batch ----------------
__global__ __launch_bounds__(256) void pool_kernel(const u32* __restrict__ z,
                                                   const float* __restrict__ ss,
                                                   const int* __restrict__ goffs,
                                                   float* __restrict__ g) {
    __shared__ float4 red[256];
    int t = threadIdx.x;
    int tc = t & 15, tr = t >> 4;
    int gr = blockIdx.x;
    int beg = goffs[gr], end = goffs[gr + 1];
    const uint2* z2 = (const uint2*)z;
    float4 acc = make_float4(0.f, 0.f, 0.f, 0.f);
    for (int n = beg + tr; n < end; n += 16) {
        uint2 v = z2[n * 16 + tc];
        float2 a = h2f(v.x), c = h2f(v.y);
        acc.x += a.x; acc.y += a.y; acc.z += c.x; acc.w += c.y;
    }
    red[tr * 16 + tc] = acc;
    for (int s = 8; s > 0; s >>= 1) {
        __syncthreads();
        if (tr < s) {
            float4 o = red[(tr + s) * 16 + tc];
            float4 m = red[tr * 16 + tc];
            m.x += o.x; m.y += o.y; m.z += o.z; m.w += o.w;
            red[tr * 16 + tc] = m;
        }
    }
    __syncthreads();
    if (tr == 0) {
        float4 sum = red[tc];
        float4 sc = ((const float4*)ss)[tc];
        float4 sh = ((const float4*)(ss + C))[tc];
        float cnt = (float)(end - beg);
        float4 o;
        o.x = fmaf(sum.x, sc.x, cnt * sh.x);
        o.y = fmaf(sum.y, sc.y, cnt * sh.y);
        o.z = fmaf(sum.z, sc.z, cnt * sh.z);
        o.w = fmaf(sum.w, sc.w, cnt * sh.w);
        ((float4*)g)[gr * 16 + tc] = o;
    }
}

// ---------------- head ----------------
__global__ __launch_bounds__(256) void head_kernel(const float* __restrict__ g,
                                                   const float* __restrict__ fc1W,
                                                   const float* __restrict__ fc1b,
                                                   const float* __restrict__ fc2W,
                                                   const float* __restrict__ fc2b,
                                                   float* __restrict__ out) {
    __shared__ float W1s[C * C];
    __shared__ float W2s[C * 16];
    __shared__ float gs[4][C], t1s[4][C];
    int t = threadIdx.x;
    for (int i = t; i < C * C; i += 256) W1s[i] = fc1W[i];
    for (int i = t; i < C * 16; i += 256) W2s[i] = fc2W[i];
    int ch = t & 63, rr = t >> 6;
    int g0 = blockIdx.x * 4;
    gs[rr][ch] = g[(g0 + rr) * C + ch];
    __syncthreads();
    float a1 = fc1b[ch];
#pragma unroll 8
    for (int k = 0; k < C; ++k) a1 = fmaf(gs[rr][k], W1s[k * C + ch], a1);
    t1s[rr][ch] = fmaxf(a1, 0.f);
    __syncthreads();
    if (t < 64) {
        int o = t & 15, r2 = t >> 4;
        float a2 = fc2b[o];
#pragma unroll 8
        for (int k = 0; k < C; ++k) a2 = fmaf(t1s[r2][k], W2s[k * 16 + o], a2);
        out[(g0 + r2) * 16 + o] = a2;
    }
}

extern "C" void kernel_launch(void* const* d_in, const int* in_sizes, int n_in,
                              void* d_out, int out_size, void* d_ws, size_t ws_size,
                              hipStream_t stream) {
    const float* x    = (const float*)d_in[0];
    const int*   ei   = (const int*)d_in[1];
    const int*   batch= (const int*)d_in[2];
    const float* encW = (const float*)d_in[3];
    const float* encb = (const float*)d_in[4];
    const float* cW1  = (const float*)d_in[5];
    const float* cb1  = (const float*)d_in[6];
    const float* cW2  = (const float*)d_in[7];
    const float* cb2  = (const float*)d_in[8];
    const float* gam  = (const float*)d_in[9];
    const float* bet  = (const float*)d_in[10];
    const float* f1W  = (const float*)d_in[11];
    const float* f1b  = (const float*)d_in[12];
    const float* f2W  = (const float*)d_in[13];
    const float* f2b  = (const float*)d_in[14];
    float* out = (float*)d_out;

    char* ws = (char*)d_ws;
    u32*   zA      = (u32*)  (ws);                    // fp16: 6.4 MB
    u32*   zB      = (u32*)  (ws + 6400000);          // fp16: 6.4 MB
    u16*   csr     = (u16*)  (ws + 12800000);         // 1.6 MB
    u32*   staged  = (u32*)  (ws + 16000000);         // 3.2 MB
    int*   offs    = (int*)  (ws + 19200000);         // 50001 ints
    int*   bcount  = (int*)  (ws + 19400064);         // 196 ints
    int*   bbase   = (int*)  (ws + 19401088);         // 197 ints
    int*   bcursor = (int*)  (ws + 19402112);         // 196 ints
    float* stats   = (float*)(ws + 19403136);         // 5*128 floats
    float* ssb     = (float*)(ws + 19405696);         // 5*128 floats
    int*   goffs   = (int*)  (ws + 19408256);         // 513 ints
    float* gpool   = (float*)(ws + 19410432);         // 128 KB

    // --- bucketed CSR build + graph offsets (once per call) ---
    hipMemsetAsync(bcount, 0, NBUCK * sizeof(int), stream);
    hipMemsetAsync(stats, 0, 5 * 2 * C * sizeof(float), stream);
    csr_hist<<<NBUCK, 256, 0, stream>>>(ei, bcount);
    csr_bscan<<<1, 256, 0, stream>>>(bcount, bbase, bcursor, offs);
    csr_stage<<<NBUCK, 256, 0, stream>>>(ei, bcursor, staged);
    csr_finalize<<<NBUCK, 256, 0, stream>>>(staged, bbase, csr, offs);
    gstart_kernel<<<SCAN_BLOCKS, 256, 0, stream>>>(batch, goffs);

    enc_kernel<<<(N_NODES + 127) / 128, 256, 0, stream>>>(x, encW, encb, zA);

    u32* zin = zA;
    u32* zout = zB;
    for (int l = 0; l < N_LAYERS; ++l) {
        const float* ss_prev = (l > 0) ? (ssb + (size_t)(l - 1) * 2 * C) : ssb;
        mlp_gather_kernel<<<(N_NODES + 31) / 32, 256, 0, stream>>>(
            csr, offs, zin, ss_prev, l > 0 ? 1 : 0, zout,
            cW1 + (size_t)l * C * C, cb1 + (size_t)l * C,
            cW2 + (size_t)l * C * C, cb2 + (size_t)l * C,
            stats + (size_t)l * 2 * C);
        bn_finalize<<<1, 64, 0, stream>>>(stats + (size_t)l * 2 * C,
                                          gam + (size_t)l * C, bet + (size_t)l * C,
                                          ssb + (size_t)l * 2 * C);
        u32* tmp = zin; zin = zout; zout = tmp;
    }

    // zin holds layer-5 pre-BN output (fp16); pool applies final BN
    pool_kernel<<<N_GRAPHS, 256, 0, stream>>>(zin, ssb + (size_t)(N_LAYERS - 1) * 2 * C, goffs, gpool);
    head_kernel<<<N_GRAPHS / 4, 256, 0, stream>>>(gpool, f1W, f1b, f2W, f2b, out);
}

// Round 12
// 465.313 us; speedup vs baseline: 1.0475x; 1.0475x over previous
//
#include <hip/hip_runtime.h>
#include <hip/hip_fp16.h>

#define N_NODES 50000
#define N_EDGES 800000
#define NODE_DIM 128
#define C 64
#define N_GRAPHS 512
#define N_LAYERS 5
#define BN_EPS 1e-5f

#define SCAN_BLOCKS 196   // ceil(50000/256)
#define NBUCK 196         // buckets of 256 nodes: bucket = dst >> 8
#define ECHUNK 4096       // edges per block in CSR-build passes
#define PLANE 800000      // u32 words per channel-plane (50000 nodes * 16 words)

typedef unsigned int u32;
typedef unsigned short u16;
typedef u32 u32x4 __attribute__((ext_vector_type(4)));  // native vec for nontemporal builtin

// fp16 helpers: 2 ch per u32 word
__device__ inline float2 h2f(u32 v) {
    __half2 h; __builtin_memcpy(&h, &v, 4);
    return __half22float2(h);
}
__device__ inline u32 f2h2(float a, float b) {
    __half2 h = __floats2half2_rn(a, b);
    u32 v; __builtin_memcpy(&v, &h, 4);
    return v;
}

// =============================================================
// encoder: z = x @ enc_W + enc_b, z stored fp16 in two channel-planes
// plane p holds ch [p*32, p*32+32): 16 u32 words per node, 3.2 MB each.
// =============================================================
__global__ __launch_bounds__(256) void enc_kernel(const float* __restrict__ x,
                                                  const float* __restrict__ W,
                                                  const float* __restrict__ b,
                                                  u32* __restrict__ z) {
    __shared__ float As[64 * 132];        // [k][row], row-dim padded
    __shared__ float Ws[NODE_DIM * C];    // 32 KB, full K
    int t = threadIdx.x;
    int tc = t & 15, tr = t >> 4;
    for (int i = t; i < NODE_DIM * C; i += 256) Ws[i] = W[i];
    int row0 = blockIdx.x * 128;
    float4 bv = ((const float4*)b)[tc];
    float acc[8][4];
#pragma unroll
    for (int i = 0; i < 8; ++i) { acc[i][0] = bv.x; acc[i][1] = bv.y; acc[i][2] = bv.z; acc[i][3] = bv.w; }

    for (int kc = 0; kc < 2; ++kc) {
        __syncthreads();
        for (int it = 0; it < 8; ++it) {
            int idx = t + 256 * it;
            int r = idx >> 4, f4 = idx & 15;
            int grow = row0 + r;
            float4 v = (grow < N_NODES) ? ((const float4*)x)[grow * 32 + kc * 16 + f4]
                                        : make_float4(0.f, 0.f, 0.f, 0.f);
            int k4 = f4 * 4;
            As[(k4 + 0) * 132 + r] = v.x;
            As[(k4 + 1) * 132 + r] = v.y;
            As[(k4 + 2) * 132 + r] = v.z;
            As[(k4 + 3) * 132 + r] = v.w;
        }
        __syncthreads();
#pragma unroll 4
        for (int k = 0; k < 64; ++k) {
            const float* ap = As + k * 132 + tr * 8;
            float4 a0 = *(const float4*)(ap);
            float4 a1 = *(const float4*)(ap + 4);
            float4 w = *(const float4*)(Ws + (kc * 64 + k) * C + tc * 4);
            float av[8] = {a0.x, a0.y, a0.z, a0.w, a1.x, a1.y, a1.z, a1.w};
#pragma unroll
            for (int i = 0; i < 8; ++i) {
                acc[i][0] = fmaf(av[i], w.x, acc[i][0]);
                acc[i][1] = fmaf(av[i], w.y, acc[i][1]);
                acc[i][2] = fmaf(av[i], w.z, acc[i][2]);
                acc[i][3] = fmaf(av[i], w.w, acc[i][3]);
            }
        }
    }
    u32* zp = z + (tc >> 3) * PLANE;      // plane for ch tc*4..tc*4+3
#pragma unroll
    for (int i = 0; i < 8; ++i) {
        int grow = row0 + tr * 8 + i;
        if (grow < N_NODES) {
            uint2 o;
            o.x = f2h2(acc[i][0], acc[i][1]);
            o.y = f2h2(acc[i][2], acc[i][3]);
            ((uint2*)zp)[grow * 8 + (tc & 7)] = o;
        }
    }
}

// ================= bucketed CSR build =================
__global__ __launch_bounds__(256) void csr_hist(const int* __restrict__ ei,
                                                int* __restrict__ bcount) {
    __shared__ int lhist[NBUCK];
    int t = threadIdx.x;
    if (t < NBUCK) lhist[t] = 0;
    __syncthreads();
    int e0 = blockIdx.x * ECHUNK;
    int e1 = min(e0 + ECHUNK, N_EDGES);
    for (int e = e0 + t; e < e1; e += 256)
        atomicAdd(&lhist[ei[N_EDGES + e] >> 8], 1);
    __syncthreads();
    if (t < NBUCK && lhist[t] > 0) atomicAdd(&bcount[t], lhist[t]);
}

__global__ __launch_bounds__(256) void csr_bscan(const int* __restrict__ bcount,
                                                 int* __restrict__ bbase,
                                                 int* __restrict__ bcursor,
                                                 int* __restrict__ offs) {
    __shared__ int s[256];
    int t = threadIdx.x;
    int v = (t < NBUCK) ? bcount[t] : 0;
    s[t] = v;
    for (int off = 1; off < 256; off <<= 1) {
        __syncthreads();
        int x = (t >= off) ? s[t - off] : 0;
        __syncthreads();
        s[t] += x;
    }
    __syncthreads();
    if (t < NBUCK) {
        bbase[t + 1] = s[t];
        bcursor[t] = s[t] - v;   // exclusive base = cursor seed
    }
    if (t == 0) { bbase[0] = 0; offs[N_NODES] = N_EDGES; }
}

// A2: stage entries bucket-major; entry = src | (dstLow8 << 16)
__global__ __launch_bounds__(256) void csr_stage(const int* __restrict__ ei,
                                                 int* __restrict__ bcursor,
                                                 u32* __restrict__ staged) {
    __shared__ int lhist[NBUCK];
    __shared__ int lbase[NBUCK];
    __shared__ int lcur[NBUCK];
    int t = threadIdx.x;
    if (t < NBUCK) lhist[t] = 0;
    __syncthreads();
    int e0 = blockIdx.x * ECHUNK;
    int e1 = min(e0 + ECHUNK, N_EDGES);
    for (int e = e0 + t; e < e1; e += 256)
        atomicAdd(&lhist[ei[N_EDGES + e] >> 8], 1);
    __syncthreads();
    if (t < NBUCK) {
        int c = lhist[t];
        lbase[t] = (c > 0) ? atomicAdd(&bcursor[t], c) : 0;
        lcur[t] = 0;
    }
    __syncthreads();
    for (int e = e0 + t; e < e1; e += 256) {
        int src = ei[e];
        int dst = ei[N_EDGES + e];
        int bk = dst >> 8;
        int r = atomicAdd(&lcur[bk], 1);
        staged[lbase[bk] + r] = (u32)src | ((u32)(dst & 255) << 16);
    }
}

// B: per-bucket counting sort -> csr (u16) + per-node offs
__global__ __launch_bounds__(256) void csr_finalize(const u32* __restrict__ staged,
                                                    const int* __restrict__ bbase,
                                                    u16* __restrict__ csr,
                                                    int* __restrict__ offs) {
    __shared__ int lhist[256];
    __shared__ int lexc[256];
    __shared__ int lcur[256];
    int t = threadIdx.x;
    int b = blockIdx.x;
    int sbeg = bbase[b], send = bbase[b + 1];
    lhist[t] = 0;
    __syncthreads();
    for (int i = sbeg + t; i < send; i += 256)
        atomicAdd(&lhist[(staged[i] >> 16) & 255], 1);
    __syncthreads();
    int v = lhist[t];
    lexc[t] = v;
    for (int off = 1; off < 256; off <<= 1) {
        __syncthreads();
        int x = (t >= off) ? lexc[t - off] : 0;
        __syncthreads();
        lexc[t] += x;
    }
    __syncthreads();
    int excl = lexc[t] - v;
    int node = b * 256 + t;
    if (node < N_NODES) offs[node] = sbeg + excl;
    lcur[t] = excl;
    __syncthreads();
    for (int i = sbeg + t; i < send; i += 256) {
        u32 ent = staged[i];
        int dlow = (ent >> 16) & 255;
        int r = atomicAdd(&lcur[dlow], 1);
        csr[sbeg + r] = (u16)(ent & 0xFFFFu);
    }
}

// ---------------- graph start offsets from sorted batch ----------------
__global__ __launch_bounds__(256) void gstart_kernel(const int* __restrict__ batch,
                                                     int* __restrict__ goffs) {
    int n = blockIdx.x * 256 + threadIdx.x;
    if (n >= N_NODES) return;
    if (n == 0) {
        for (int g = 0; g <= batch[0]; ++g) goffs[g] = 0;
    } else {
        int bp = batch[n - 1], bc = batch[n];
        for (int g = bp + 1; g <= bc; ++g) goffs[g] = n;
    }
    if (n == N_NODES - 1) {
        for (int g = batch[n] + 1; g <= N_GRAPHS; ++g) goffs[g] = N_NODES;
    }
}

// =============================================================
// planar gather + BN-apply, one dispatch per plane (phase-separated so
// the 3.2 MB plane is L2-resident per XCD during its pass).
// y[n, plane-ch] = sc*(z[n] + sum_src z[src]) + (deg+1)*sh
// 4 lanes/node x uint4 (16 B = 8 fp16 ch). y written nontemporal.
// =============================================================
__global__ __launch_bounds__(256, 8) void gather_plane_kernel(const u16* __restrict__ csr_src,
                                                              const int* __restrict__ offs,
                                                              const u32* __restrict__ z_base,
                                                              int plane,
                                                              const float* __restrict__ ss,
                                                              int use_ss,
                                                              u32* __restrict__ y_base) {
    int t = threadIdx.x;
    int tg = t & 3;                        // which 16B of the 64B plane-row
    int node = blockIdx.x * 64 + (t >> 2);
    if (node >= N_NODES) return;
    float scv[8], shv[8];
    if (use_ss) {
        int f4i = plane * 8 + tg * 2;      // float4 index into ss for ch base
        float4 s0 = ((const float4*)ss)[f4i], s1 = ((const float4*)ss)[f4i + 1];
        float4 h0 = ((const float4*)(ss + C))[f4i], h1 = ((const float4*)(ss + C))[f4i + 1];
        scv[0] = s0.x; scv[1] = s0.y; scv[2] = s0.z; scv[3] = s0.w;
        scv[4] = s1.x; scv[5] = s1.y; scv[6] = s1.z; scv[7] = s1.w;
        shv[0] = h0.x; shv[1] = h0.y; shv[2] = h0.z; shv[3] = h0.w;
        shv[4] = h1.x; shv[5] = h1.y; shv[6] = h1.z; shv[7] = h1.w;
    } else {
#pragma unroll
        for (int i = 0; i < 8; ++i) { scv[i] = 1.f; shv[i] = 0.f; }
    }
    const uint4* zp = (const uint4*)(z_base + plane * PLANE);  // node stride 4 uint4
    float acc[8];
    {
        uint4 sv = zp[node * 4 + tg];      // self term (GIN eps=0)
        float2 p0 = h2f(sv.x), p1 = h2f(sv.y), p2 = h2f(sv.z), p3 = h2f(sv.w);
        acc[0] = p0.x; acc[1] = p0.y; acc[2] = p1.x; acc[3] = p1.y;
        acc[4] = p2.x; acc[5] = p2.y; acc[6] = p3.x; acc[7] = p3.y;
    }
    int beg = offs[node], end = offs[node + 1];
    int e = beg;
    for (; e + 3 < end; e += 4) {          // 4 independent 16B loads in flight
        int s0 = csr_src[e], s1 = csr_src[e + 1], s2 = csr_src[e + 2], s3 = csr_src[e + 3];
        uint4 v0 = zp[s0 * 4 + tg], v1 = zp[s1 * 4 + tg];
        uint4 v2 = zp[s2 * 4 + tg], v3 = zp[s3 * 4 + tg];
        float2 a0 = h2f(v0.x), a1 = h2f(v1.x), a2 = h2f(v2.x), a3 = h2f(v3.x);
        acc[0] += (a0.x + a1.x) + (a2.x + a3.x);
        acc[1] += (a0.y + a1.y) + (a2.y + a3.y);
        a0 = h2f(v0.y); a1 = h2f(v1.y); a2 = h2f(v2.y); a3 = h2f(v3.y);
        acc[2] += (a0.x + a1.x) + (a2.x + a3.x);
        acc[3] += (a0.y + a1.y) + (a2.y + a3.y);
        a0 = h2f(v0.z); a1 = h2f(v1.z); a2 = h2f(v2.z); a3 = h2f(v3.z);
        acc[4] += (a0.x + a1.x) + (a2.x + a3.x);
        acc[5] += (a0.y + a1.y) + (a2.y + a3.y);
        a0 = h2f(v0.w); a1 = h2f(v1.w); a2 = h2f(v2.w); a3 = h2f(v3.w);
        acc[6] += (a0.x + a1.x) + (a2.x + a3.x);
        acc[7] += (a0.y + a1.y) + (a2.y + a3.y);
    }
    for (; e < end; ++e) {
        uint4 v = zp[csr_src[e] * 4 + tg];
        float2 a0 = h2f(v.x), a1 = h2f(v.y), a2 = h2f(v.z), a3 = h2f(v.w);
        acc[0] += a0.x; acc[1] += a0.y; acc[2] += a1.x; acc[3] += a1.y;
        acc[4] += a2.x; acc[5] += a2.y; acc[6] += a3.x; acc[7] += a3.y;
    }
    float cnt = (float)(end - beg + 1);
#pragma unroll
    for (int i = 0; i < 8; ++i) acc[i] = fmaf(acc[i], scv[i], cnt * shv[i]);
    u32x4 o;
    o.x = f2h2(acc[0], acc[1]);
    o.y = f2h2(acc[2], acc[3]);
    o.z = f2h2(acc[4], acc[5]);
    o.w = f2h2(acc[6], acc[7]);
    u32x4* yp = (u32x4*)(y_base + plane * PLANE);
    __builtin_nontemporal_store(o, &yp[node * 4 + tg]);   // don't evict z from L2
}

// =============================================================
// MLP: z_out = relu(relu(y@W1+b1)@W2+b2) + BN stats. BM=64, fp16 LDS.
// y and z_out are planar; staging is a coalesced uint4 copy (no unpack).
// =============================================================
__global__ __launch_bounds__(256) void mlp_kernel(const u32* __restrict__ y,
                                                  u32* __restrict__ z_out,
                                                  const float* __restrict__ W1,
                                                  const float* __restrict__ b1,
                                                  const float* __restrict__ W2,
                                                  const float* __restrict__ b2,
                                                  float* __restrict__ stats) {
    __shared__ u32 Asw[32 * 68];     // 8.5 KB, fp16-packed [word][row]
    __shared__ float Ws[C * C];      // 16 KB: W1, then W2, then stats-reduce
    int t = threadIdx.x;
    int tc = t & 15, tr = t >> 4;
    for (int i = t; i < C * C; i += 256) Ws[i] = W1[i];
    int row0 = blockIdx.x * 64;

    // ---- stage y (planar packed fp16) transposed into Asw ----
    int tg = t & 7, rg = t >> 3;
    const uint4* yp = (const uint4*)(y + (tg >> 2) * PLANE);
    int q = tg & 3;
#pragma unroll
    for (int it = 0; it < 2; ++it) {
        int r = rg + 32 * it;
        int node = row0 + r;
        uint4 v = (node < N_NODES) ? yp[node * 4 + q] : make_uint4(0u, 0u, 0u, 0u);
        Asw[(tg * 4 + 0) * 68 + r] = v.x;
        Asw[(tg * 4 + 1) * 68 + r] = v.y;
        Asw[(tg * 4 + 2) * 68 + r] = v.z;
        Asw[(tg * 4 + 3) * 68 + r] = v.w;
    }
    __syncthreads();

    // ---- GEMM1: t1 = relu(y@W1+b1), TM=4 x TN=4 ----
    float4 b1v = ((const float4*)b1)[tc];
    float a[4][4];
#pragma unroll
    for (int i = 0; i < 4; ++i) { a[i][0] = b1v.x; a[i][1] = b1v.y; a[i][2] = b1v.z; a[i][3] = b1v.w; }
#pragma unroll 2
    for (int w = 0; w < 32; ++w) {
        uint4 aw = *(const uint4*)(Asw + w * 68 + tr * 4);  // rows tr*4..+3, ch {2w,2w+1}
        float2 r0 = h2f(aw.x), r1 = h2f(aw.y), r2 = h2f(aw.z), r3 = h2f(aw.w);
        float4 w0 = *(const float4*)(Ws + (2 * w) * C + tc * 4);
        float4 w1 = *(const float4*)(Ws + (2 * w + 1) * C + tc * 4);
        float e0[4] = {r0.x, r1.x, r2.x, r3.x};
        float e1[4] = {r0.y, r1.y, r2.y, r3.y};
#pragma unroll
        for (int i = 0; i < 4; ++i) {
            a[i][0] = fmaf(e0[i], w0.x, a[i][0]); a[i][0] = fmaf(e1[i], w1.x, a[i][0]);
            a[i][1] = fmaf(e0[i], w0.y, a[i][1]); a[i][1] = fmaf(e1[i], w1.y, a[i][1]);
            a[i][2] = fmaf(e0[i], w0.z, a[i][2]); a[i][2] = fmaf(e1[i], w1.z, a[i][2]);
            a[i][3] = fmaf(e0[i], w0.w, a[i][3]); a[i][3] = fmaf(e1[i], w1.w, a[i][3]);
        }
    }
    __syncthreads();  // Asw + Ws(W1) reads done

    // ---- restage t1^T (fp16) into Asw; load W2 ----
    {
        uint4 w0, w1;
        w0.x = f2h2(fmaxf(a[0][0], 0.f), fmaxf(a[0][1], 0.f));
        w0.y = f2h2(fmaxf(a[1][0], 0.f), fmaxf(a[1][1], 0.f));
        w0.z = f2h2(fmaxf(a[2][0], 0.f), fmaxf(a[2][1], 0.f));
        w0.w = f2h2(fmaxf(a[3][0], 0.f), fmaxf(a[3][1], 0.f));
        w1.x = f2h2(fmaxf(a[0][2], 0.f), fmaxf(a[0][3], 0.f));
        w1.y = f2h2(fmaxf(a[1][2], 0.f), fmaxf(a[1][3], 0.f));
        w1.z = f2h2(fmaxf(a[2][2], 0.f), fmaxf(a[2][3], 0.f));
        w1.w = f2h2(fmaxf(a[3][2], 0.f), fmaxf(a[3][3], 0.f));
        *(uint4*)(Asw + (tc * 2) * 68 + tr * 4) = w0;       // ch pair {tc*4, tc*4+1}
        *(uint4*)(Asw + (tc * 2 + 1) * 68 + tr * 4) = w1;   // ch pair {tc*4+2, tc*4+3}
    }
    for (int i = t; i < C * C; i += 256) Ws[i] = W2[i];
    __syncthreads();

    // ---- GEMM2: z = relu(t1@W2+b2) ----
    float4 b2v = ((const float4*)b2)[tc];
#pragma unroll
    for (int i = 0; i < 4; ++i) { a[i][0] = b2v.x; a[i][1] = b2v.y; a[i][2] = b2v.z; a[i][3] = b2v.w; }
#pragma unroll 2
    for (int w = 0; w < 32; ++w) {
        uint4 aw = *(const uint4*)(Asw + w * 68 + tr * 4);
        float2 r0 = h2f(aw.x), r1 = h2f(aw.y), r2 = h2f(aw.z), r3 = h2f(aw.w);
        float4 w0 = *(const float4*)(Ws + (2 * w) * C + tc * 4);
        float4 w1 = *(const float4*)(Ws + (2 * w + 1) * C + tc * 4);
        float e0[4] = {r0.x, r1.x, r2.x, r3.x};
        float e1[4] = {r0.y, r1.y, r2.y, r3.y};
#pragma unroll
        for (int i = 0; i < 4; ++i) {
            a[i][0] = fmaf(e0[i], w0.x, a[i][0]); a[i][0] = fmaf(e1[i], w1.x, a[i][0]);
            a[i][1] = fmaf(e0[i], w0.y, a[i][1]); a[i][1] = fmaf(e1[i], w1.y, a[i][1]);
            a[i][2] = fmaf(e0[i], w0.z, a[i][2]); a[i][2] = fmaf(e1[i], w1.z, a[i][2]);
            a[i][3] = fmaf(e0[i], w0.w, a[i][3]); a[i][3] = fmaf(e1[i], w1.w, a[i][3]);
        }
    }

    // ---- relu, fp16 planar store, local BN stats (fp32) ----
    float lsum[4] = {0.f, 0.f, 0.f, 0.f};
    float lsq[4] = {0.f, 0.f, 0.f, 0.f};
    u32* zo = z_out + (tc >> 3) * PLANE;
#pragma unroll
    for (int i = 0; i < 4; ++i) {
        int grow = row0 + tr * 4 + i;
        if (grow < N_NODES) {
            float o0 = fmaxf(a[i][0], 0.f), o1 = fmaxf(a[i][1], 0.f);
            float o2 = fmaxf(a[i][2], 0.f), o3 = fmaxf(a[i][3], 0.f);
            uint2 o;
            o.x = f2h2(o0, o1);
            o.y = f2h2(o2, o3);
            ((uint2*)zo)[grow * 8 + (tc & 7)] = o;
            lsum[0] += o0; lsum[1] += o1; lsum[2] += o2; lsum[3] += o3;
            lsq[0] += o0 * o0; lsq[1] += o1 * o1; lsq[2] += o2 * o2; lsq[3] += o3 * o3;
        }
    }
    __syncthreads();  // Ws(W2) reads done; reuse as reduction buffer 16x128
    float* red = Ws;
#pragma unroll
    for (int j = 0; j < 4; ++j) {
        red[tr * 128 + tc * 4 + j] = lsum[j];
        red[tr * 128 + 64 + tc * 4 + j] = lsq[j];
    }
    __syncthreads();
    if (t < 128) {
        float s = 0.f;
#pragma unroll
        for (int r = 0; r < 16; ++r) s += red[r * 128 + t];
        atomicAdd(&stats[t], s);  // [0..63]=sum, [64..127]=sumsq
    }
}

// ---------------- BN finalize ----------------
__global__ void bn_finalize(const float* __restrict__ stats,
                            const float* __restrict__ gamma,
                            const float* __restrict__ beta,
                            float* __restrict__ ss) {
    int c = threadIdx.x;
    if (c >= C) return;
    const float invN = 1.0f / (float)N_NODES;
    float mean = stats[c] * invN;
    float var = stats[C + c] * invN - mean * mean;
    float rstd = rsqrtf(var + BN_EPS);
    float sc = gamma[c] * rstd;
    ss[c] = sc;
    ss[C + c] = beta[c] - mean * sc;
}

// ---------------- pool: segmented reduction over sorted batch (planar z) ----------------
__global__ __launch_bounds__(256) void pool_kernel(const u32* __restrict__ z,
                                                   const float* __restrict__ ss,
                                                   const int* __restrict__ goffs,
                                                   float* __restrict__ g) {
    __shared__ float4 red[256];
    int t = threadIdx.x;
    int tc = t & 15, tr = t >> 4;
    int gr = blockIdx.x;
    int beg = goffs[gr], end = goffs[gr + 1];
    const uint2* zp = (const uint2*)(z + (tc >> 3) * PLANE);
    int w = tc & 7;
    float4 acc = make_float4(0.f, 0.f, 0.f, 0.f);
    for (int n = beg + tr; n < end; n += 16) {
        uint2 v = zp[n * 8 + w];
        float2 a = h2f(v.x), c = h2f(v.y);
        acc.x += a.x; acc.y += a.y; acc.z += c.x; acc.w += c.y;
    }
    red[tr * 16 + tc] = acc;
    for (int s = 8; s > 0; s >>= 1) {
        __syncthreads();
        if (tr < s) {
            float4 o = red[(tr + s) * 16 + tc];
            float4 m = red[tr * 16 + tc];
            m.x += o.x; m.y += o.y; m.z += o.z; m.w += o.w;
            red[tr * 16 + tc] = m;
        }
    }
    __syncthreads();
    if (tr == 0) {
        float4 sum = red[tc];
        float4 sc = ((const float4*)ss)[tc];
        float4 sh = ((const float4*)(ss + C))[tc];
        float cnt = (float)(end - beg);
        float4 o;
        o.x = fmaf(sum.x, sc.x, cnt * sh.x);
        o.y = fmaf(sum.y, sc.y, cnt * sh.y);
        o.z = fmaf(sum.z, sc.z, cnt * sh.z);
        o.w = fmaf(sum.w, sc.w, cnt * sh.w);
        ((float4*)g)[gr * 16 + tc] = o;
    }
}

// ---------------- head ----------------
__global__ __launch_bounds__(256) void head_kernel(const float* __restrict__ g,
                                                   const float* __restrict__ fc1W,
                                                   const float* __restrict__ fc1b,
                                                   const float* __restrict__ fc2W,
                                                   const float* __restrict__ fc2b,
                                                   float* __restrict__ out) {
    __shared__ float W1s[C * C];
    __shared__ float W2s[C * 16];
    __shared__ float gs[4][C], t1s[4][C];
    int t = threadIdx.x;
    for (int i = t; i < C * C; i += 256) W1s[i] = fc1W[i];
    for (int i = t; i < C * 16; i += 256) W2s[i] = fc2W[i];
    int ch = t & 63, rr = t >> 6;
    int g0 = blockIdx.x * 4;
    gs[rr][ch] = g[(g0 + rr) * C + ch];
    __syncthreads();
    float a1 = fc1b[ch];
#pragma unroll 8
    for (int k = 0; k < C; ++k) a1 = fmaf(gs[rr][k], W1s[k * C + ch], a1);
    t1s[rr][ch] = fmaxf(a1, 0.f);
    __syncthreads();
    if (t < 64) {
        int o = t & 15, r2 = t >> 4;
        float a2 = fc2b[o];
#pragma unroll 8
        for (int k = 0; k < C; ++k) a2 = fmaf(t1s[r2][k], W2s[k * 16 + o], a2);
        out[(g0 + r2) * 16 + o] = a2;
    }
}

extern "C" void kernel_launch(void* const* d_in, const int* in_sizes, int n_in,
                              void* d_out, int out_size, void* d_ws, size_t ws_size,
                              hipStream_t stream) {
    const float* x    = (const float*)d_in[0];
    const int*   ei   = (const int*)d_in[1];
    const int*   batch= (const int*)d_in[2];
    const float* encW = (const float*)d_in[3];
    const float* encb = (const float*)d_in[4];
    const float* cW1  = (const float*)d_in[5];
    const float* cb1  = (const float*)d_in[6];
    const float* cW2  = (const float*)d_in[7];
    const float* cb2  = (const float*)d_in[8];
    const float* gam  = (const float*)d_in[9];
    const float* bet  = (const float*)d_in[10];
    const float* f1W  = (const float*)d_in[11];
    const float* f1b  = (const float*)d_in[12];
    const float* f2W  = (const float*)d_in[13];
    const float* f2b  = (const float*)d_in[14];
    float* out = (float*)d_out;

    char* ws = (char*)d_ws;
    u32*   zA      = (u32*)  (ws);                    // fp16 planar: 6.4 MB (2 planes)
    u32*   zB      = (u32*)  (ws + 6400000);          // fp16 planar: 6.4 MB
    u32*   ybuf    = (u32*)  (ws + 12800000);         // fp16 planar: 6.4 MB
    u16*   csr     = (u16*)  (ws + 19200000);         // 1.6 MB
    u32*   staged  = (u32*)  (ws + 20800000);         // 3.2 MB
    int*   offs    = (int*)  (ws + 24000000);         // 50001 ints
    int*   bcount  = (int*)  (ws + 24200064);         // 196 ints
    int*   bbase   = (int*)  (ws + 24201088);         // 197 ints
    int*   bcursor = (int*)  (ws + 24202112);         // 196 ints
    float* stats   = (float*)(ws + 24203136);         // 5*128 floats
    float* ssb     = (float*)(ws + 24205696);         // 5*128 floats
    int*   goffs   = (int*)  (ws + 24208256);         // 513 ints
    float* gpool   = (float*)(ws + 24210432);         // 128 KB

    // --- bucketed CSR build + graph offsets (once per call) ---
    hipMemsetAsync(bcount, 0, NBUCK * sizeof(int), stream);
    hipMemsetAsync(stats, 0, 5 * 2 * C * sizeof(float), stream);
    csr_hist<<<NBUCK, 256, 0, stream>>>(ei, bcount);
    csr_bscan<<<1, 256, 0, stream>>>(bcount, bbase, bcursor, offs);
    csr_stage<<<NBUCK, 256, 0, stream>>>(ei, bcursor, staged);
    csr_finalize<<<NBUCK, 256, 0, stream>>>(staged, bbase, csr, offs);
    gstart_kernel<<<SCAN_BLOCKS, 256, 0, stream>>>(batch, goffs);

    enc_kernel<<<(N_NODES + 127) / 128, 256, 0, stream>>>(x, encW, encb, zA);

    u32* zin = zA;
    u32* zout = zB;
    for (int l = 0; l < N_LAYERS; ++l) {
        const float* ss_prev = (l > 0) ? (ssb + (size_t)(l - 1) * 2 * C) : ssb;
        // phase-separated planar gathers: each pass's working set is 3.2 MB (< 4 MB L2/XCD)
        gather_plane_kernel<<<(N_NODES + 63) / 64, 256, 0, stream>>>(
            csr, offs, zin, 0, ss_prev, l > 0 ? 1 : 0, ybuf);
        gather_plane_kernel<<<(N_NODES + 63) / 64, 256, 0, stream>>>(
            csr, offs, zin, 1, ss_prev, l > 0 ? 1 : 0, ybuf);
        mlp_kernel<<<(N_NODES + 63) / 64, 256, 0, stream>>>(
            ybuf, zout,
            cW1 + (size_t)l * C * C, cb1 + (size_t)l * C,
            cW2 + (size_t)l * C * C, cb2 + (size_t)l * C,
            stats + (size_t)l * 2 * C);
        bn_finalize<<<1, 64, 0, stream>>>(stats + (size_t)l * 2 * C,
                                          gam + (size_t)l * C, bet + (size_t)l * C,
                                          ssb + (size_t)l * 2 * C);
        u32* tmp = zin; zin = zout; zout = tmp;
    }

    // zin holds layer-5 pre-BN output (fp16 planar); pool applies final BN
    pool_kernel<<<N_GRAPHS, 256, 0, stream>>>(zin, ssb + (size_t)(N_LAYERS - 1) * 2 * C, goffs, gpool);
    head_kernel<<<N_GRAPHS / 4, 256, 0, stream>>>(gpool, f1W, f1b, f2W, f2b, out);
}

// Round 13
// 375.617 us; speedup vs baseline: 1.2976x; 1.2388x over previous
//
#include <hip/hip_runtime.h>
#include <hip/hip_fp16.h>

#define N_NODES 50000
#define N_EDGES 800000
#define NODE_DIM 128
#define C 64
#define N_GRAPHS 512
#define N_LAYERS 5
#define BN_EPS 1e-5f

#define SCAN_BLOCKS 196   // ceil(50000/256)
#define NBUCK 196         // buckets of 256 nodes: bucket = dst >> 8
#define ECHUNK 4096       // edges per block in CSR-build passes
#define BCAP 5120         // fixed bucket capacity (mean 4096, sigma ~64 -> 16 sigma headroom)

typedef unsigned int u32;
typedef unsigned short u16;

// fp16 helpers: 2 ch per u32 word
__device__ inline float2 h2f(u32 v) {
    __half2 h; __builtin_memcpy(&h, &v, 4);
    return __half22float2(h);
}
__device__ inline u32 f2h2(float a, float b) {
    __half2 h = __floats2half2_rn(a, b);
    u32 v; __builtin_memcpy(&v, &h, 4);
    return v;
}
__device__ inline void acc8(float* acc, uint4 v) {
    float2 a0 = h2f(v.x), a1 = h2f(v.y), a2 = h2f(v.z), a3 = h2f(v.w);
    acc[0] += a0.x; acc[1] += a0.y; acc[2] += a1.x; acc[3] += a1.y;
    acc[4] += a2.x; acc[5] += a2.y; acc[6] += a3.x; acc[7] += a3.y;
}

// =============================================================
// encoder: z = x @ enc_W + enc_b   [50000,128]x[128,64], z stored fp16
// (interleaved: node row = 16 uint2 = 128 B)
// =============================================================
__global__ __launch_bounds__(256) void enc_kernel(const float* __restrict__ x,
                                                  const float* __restrict__ W,
                                                  const float* __restrict__ b,
                                                  u32* __restrict__ z) {
    __shared__ float As[64 * 132];        // [k][row], row-dim padded
    __shared__ float Ws[NODE_DIM * C];    // 32 KB, full K
    int t = threadIdx.x;
    int tc = t & 15, tr = t >> 4;
    for (int i = t; i < NODE_DIM * C; i += 256) Ws[i] = W[i];
    int row0 = blockIdx.x * 128;
    float4 bv = ((const float4*)b)[tc];
    float acc[8][4];
#pragma unroll
    for (int i = 0; i < 8; ++i) { acc[i][0] = bv.x; acc[i][1] = bv.y; acc[i][2] = bv.z; acc[i][3] = bv.w; }

    for (int kc = 0; kc < 2; ++kc) {
        __syncthreads();
        for (int it = 0; it < 8; ++it) {
            int idx = t + 256 * it;
            int r = idx >> 4, f4 = idx & 15;
            int grow = row0 + r;
            float4 v = (grow < N_NODES) ? ((const float4*)x)[grow * 32 + kc * 16 + f4]
                                        : make_float4(0.f, 0.f, 0.f, 0.f);
            int k4 = f4 * 4;
            As[(k4 + 0) * 132 + r] = v.x;
            As[(k4 + 1) * 132 + r] = v.y;
            As[(k4 + 2) * 132 + r] = v.z;
            As[(k4 + 3) * 132 + r] = v.w;
        }
        __syncthreads();
#pragma unroll 4
        for (int k = 0; k < 64; ++k) {
            const float* ap = As + k * 132 + tr * 8;
            float4 a0 = *(const float4*)(ap);
            float4 a1 = *(const float4*)(ap + 4);
            float4 w = *(const float4*)(Ws + (kc * 64 + k) * C + tc * 4);
            float av[8] = {a0.x, a0.y, a0.z, a0.w, a1.x, a1.y, a1.z, a1.w};
#pragma unroll
            for (int i = 0; i < 8; ++i) {
                acc[i][0] = fmaf(av[i], w.x, acc[i][0]);
                acc[i][1] = fmaf(av[i], w.y, acc[i][1]);
                acc[i][2] = fmaf(av[i], w.z, acc[i][2]);
                acc[i][3] = fmaf(av[i], w.w, acc[i][3]);
            }
        }
    }
#pragma unroll
    for (int i = 0; i < 8; ++i) {
        int grow = row0 + tr * 8 + i;
        if (grow < N_NODES) {
            uint2 o;
            o.x = f2h2(acc[i][0], acc[i][1]);
            o.y = f2h2(acc[i][2], acc[i][3]);
            ((uint2*)z)[grow * 16 + tc] = o;
        }
    }
}

// ================= single-pass bucketed CSR build =================
__global__ void seed_kernel(int* __restrict__ bcursor) {
    int t = threadIdx.x;
    if (t < NBUCK) bcursor[t] = t * BCAP;
}

// stage entries bucket-major via direct range reservation; entry = src | (dstLow8 << 16)
__global__ __launch_bounds__(256) void csr_stage(const int* __restrict__ ei,
                                                 int* __restrict__ bcursor,
                                                 u32* __restrict__ staged) {
    __shared__ int lhist[NBUCK];
    __shared__ int lbase[NBUCK];
    __shared__ int lcur[NBUCK];
    int t = threadIdx.x;
    if (t < NBUCK) lhist[t] = 0;
    __syncthreads();
    int e0 = blockIdx.x * ECHUNK;
    int e1 = min(e0 + ECHUNK, N_EDGES);
    for (int e = e0 + t; e < e1; e += 256)
        atomicAdd(&lhist[ei[N_EDGES + e] >> 8], 1);
    __syncthreads();
    if (t < NBUCK) {
        int c = lhist[t];
        lbase[t] = (c > 0) ? atomicAdd(&bcursor[t], c) : 0;   // contiguous run inside bucket
        lcur[t] = 0;
    }
    __syncthreads();
    for (int e = e0 + t; e < e1; e += 256) {
        int src = ei[e];
        int dst = ei[N_EDGES + e];
        int bk = dst >> 8;
        int r = atomicAdd(&lcur[bk], 1);
        staged[lbase[bk] + r] = (u32)src | ((u32)(dst & 255) << 16);
    }
}

// per-bucket counting sort -> csr (u16) + per-node [offs, ends)
__global__ __launch_bounds__(256) void csr_finalize(const u32* __restrict__ staged,
                                                    const int* __restrict__ bcursor,
                                                    u16* __restrict__ csr,
                                                    int* __restrict__ offs,
                                                    int* __restrict__ ends) {
    __shared__ int lhist[256];
    __shared__ int lexc[256];
    __shared__ int lcur[256];
    int t = threadIdx.x;
    int b = blockIdx.x;
    int sbeg = b * BCAP, send = bcursor[b];   // final cursor = sbeg + count
    lhist[t] = 0;
    __syncthreads();
    for (int i = sbeg + t; i < send; i += 256)
        atomicAdd(&lhist[(staged[i] >> 16) & 255], 1);
    __syncthreads();
    int v = lhist[t];
    lexc[t] = v;
    for (int off = 1; off < 256; off <<= 1) {
        __syncthreads();
        int x = (t >= off) ? lexc[t - off] : 0;
        __syncthreads();
        lexc[t] += x;
    }
    __syncthreads();
    int excl = lexc[t] - v;
    int node = b * 256 + t;
    if (node < N_NODES) {
        offs[node] = sbeg + excl;
        ends[node] = sbeg + excl + v;
    }
    lcur[t] = excl;
    __syncthreads();
    for (int i = sbeg + t; i < send; i += 256) {
        u32 ent = staged[i];
        int dlow = (ent >> 16) & 255;
        int r = atomicAdd(&lcur[dlow], 1);
        csr[sbeg + r] = (u16)(ent & 0xFFFFu);
    }
}

// ---------------- graph start offsets from sorted batch ----------------
__global__ __launch_bounds__(256) void gstart_kernel(const int* __restrict__ batch,
                                                     int* __restrict__ goffs) {
    int n = blockIdx.x * 256 + threadIdx.x;
    if (n >= N_NODES) return;
    if (n == 0) {
        for (int g = 0; g <= batch[0]; ++g) goffs[g] = 0;
    } else {
        int bp = batch[n - 1], bc = batch[n];
        for (int g = bp + 1; g <= bc; ++g) goffs[g] = n;
    }
    if (n == N_NODES - 1) {
        for (int g = batch[n] + 1; g <= N_GRAPHS; ++g) goffs[g] = N_NODES;
    }
}

// =============================================================
// fused gather(fp16) + in-kernel BN finalize/apply + MLP + BN stats.
// BM=64, 782 blocks, 24.5 KB LDS. Gather: 8 lanes/row x uint4, 8-deep unroll.
// =============================================================
__global__ __launch_bounds__(256) void mlp_gather_kernel(const u16* __restrict__ csr,
                                                         const int* __restrict__ offs,
                                                         const int* __restrict__ ends,
                                                         const u32* __restrict__ z_in,
                                                         const float* __restrict__ stats_prev,
                                                         const float* __restrict__ gamma_prev,
                                                         const float* __restrict__ beta_prev,
                                                         int use_ss,
                                                         u32* __restrict__ z_out,
                                                         const float* __restrict__ W1,
                                                         const float* __restrict__ b1,
                                                         const float* __restrict__ W2,
                                                         const float* __restrict__ b2,
                                                         float* __restrict__ stats_out) {
    __shared__ u32 Asw[32 * 68];     // 8.5 KB, fp16-packed [word][row]
    __shared__ float Ws[C * C];      // 16 KB: W1, then W2, then stats-reduce
    int t = threadIdx.x;
    int tc = t & 15, tr = t >> 4;
    for (int i = t; i < C * C; i += 256) Ws[i] = W1[i];
    int row0 = blockIdx.x * 64;

    // ---- per-thread BN scale/shift for channels tg*8..+7 (in-kernel finalize) ----
    int tg = t & 7, rg = t >> 3;
    float scv[8], shv[8];
    if (use_ss) {
        const float invN = 1.0f / (float)N_NODES;
#pragma unroll
        for (int i = 0; i < 8; ++i) {
            int ch = tg * 8 + i;
            float mean = stats_prev[ch] * invN;
            float var = stats_prev[C + ch] * invN - mean * mean;
            float rstd = rsqrtf(var + BN_EPS);
            float sc = gamma_prev[ch] * rstd;
            scv[i] = sc;
            shv[i] = beta_prev[ch] - mean * sc;
        }
    } else {
#pragma unroll
        for (int i = 0; i < 8; ++i) { scv[i] = 1.f; shv[i] = 0.f; }
    }

    // ---- gather + BN-apply, staged transposed into Asw ----
    const uint4* z4 = (const uint4*)z_in;
#pragma unroll
    for (int it = 0; it < 2; ++it) {
        int r = rg + 32 * it;
        int node = row0 + r;
        float acc[8] = {0.f, 0.f, 0.f, 0.f, 0.f, 0.f, 0.f, 0.f};
        if (node < N_NODES) {
            acc8(acc, z4[node * 8 + tg]);    // self term (GIN eps=0)
            int beg = offs[node], end = ends[node];
            int e = beg;
            for (; e + 7 < end; e += 8) {    // 8 independent 16B line-loads in flight
                int s0 = csr[e], s1 = csr[e + 1], s2 = csr[e + 2], s3 = csr[e + 3];
                int s4 = csr[e + 4], s5 = csr[e + 5], s6 = csr[e + 6], s7 = csr[e + 7];
                uint4 v0 = z4[s0 * 8 + tg], v1 = z4[s1 * 8 + tg];
                uint4 v2 = z4[s2 * 8 + tg], v3 = z4[s3 * 8 + tg];
                uint4 v4 = z4[s4 * 8 + tg], v5 = z4[s5 * 8 + tg];
                uint4 v6 = z4[s6 * 8 + tg], v7 = z4[s7 * 8 + tg];
                acc8(acc, v0); acc8(acc, v1); acc8(acc, v2); acc8(acc, v3);
                acc8(acc, v4); acc8(acc, v5); acc8(acc, v6); acc8(acc, v7);
            }
            for (; e + 3 < end; e += 4) {
                int s0 = csr[e], s1 = csr[e + 1], s2 = csr[e + 2], s3 = csr[e + 3];
                uint4 v0 = z4[s0 * 8 + tg], v1 = z4[s1 * 8 + tg];
                uint4 v2 = z4[s2 * 8 + tg], v3 = z4[s3 * 8 + tg];
                acc8(acc, v0); acc8(acc, v1); acc8(acc, v2); acc8(acc, v3);
            }
            for (; e < end; ++e) acc8(acc, z4[csr[e] * 8 + tg]);
            float cnt = (float)(end - beg + 1);
#pragma unroll
            for (int i = 0; i < 8; ++i) acc[i] = fmaf(acc[i], scv[i], cnt * shv[i]);
        }
        Asw[(tg * 4 + 0) * 68 + r] = f2h2(acc[0], acc[1]);
        Asw[(tg * 4 + 1) * 68 + r] = f2h2(acc[2], acc[3]);
        Asw[(tg * 4 + 2) * 68 + r] = f2h2(acc[4], acc[5]);
        Asw[(tg * 4 + 3) * 68 + r] = f2h2(acc[6], acc[7]);
    }
    __syncthreads();

    // ---- GEMM1: t1 = relu(y@W1+b1), TM=4 x TN=4 ----
    float4 b1v = ((const float4*)b1)[tc];
    float a[4][4];
#pragma unroll
    for (int i = 0; i < 4; ++i) { a[i][0] = b1v.x; a[i][1] = b1v.y; a[i][2] = b1v.z; a[i][3] = b1v.w; }
#pragma unroll 2
    for (int w = 0; w < 32; ++w) {
        uint4 aw = *(const uint4*)(Asw + w * 68 + tr * 4);  // rows tr*4..+3, ch {2w,2w+1}
        float2 r0 = h2f(aw.x), r1 = h2f(aw.y), r2 = h2f(aw.z), r3 = h2f(aw.w);
        float4 w0 = *(const float4*)(Ws + (2 * w) * C + tc * 4);
        float4 w1 = *(const float4*)(Ws + (2 * w + 1) * C + tc * 4);
        float e0[4] = {r0.x, r1.x, r2.x, r3.x};
        float e1[4] = {r0.y, r1.y, r2.y, r3.y};
#pragma unroll
        for (int i = 0; i < 4; ++i) {
            a[i][0] = fmaf(e0[i], w0.x, a[i][0]); a[i][0] = fmaf(e1[i], w1.x, a[i][0]);
            a[i][1] = fmaf(e0[i], w0.y, a[i][1]); a[i][1] = fmaf(e1[i], w1.y, a[i][1]);
            a[i][2] = fmaf(e0[i], w0.z, a[i][2]); a[i][2] = fmaf(e1[i], w1.z, a[i][2]);
            a[i][3] = fmaf(e0[i], w0.w, a[i][3]); a[i][3] = fmaf(e1[i], w1.w, a[i][3]);
        }
    }
    __syncthreads();  // Asw + Ws(W1) reads done

    // ---- restage t1^T (fp16) into Asw; load W2 ----
    {
        uint4 w0, w1;
        w0.x = f2h2(fmaxf(a[0][0], 0.f), fmaxf(a[0][1], 0.f));
        w0.y = f2h2(fmaxf(a[1][0], 0.f), fmaxf(a[1][1], 0.f));
        w0.z = f2h2(fmaxf(a[2][0], 0.f), fmaxf(a[2][1], 0.f));
        w0.w = f2h2(fmaxf(a[3][0], 0.f), fmaxf(a[3][1], 0.f));
        w1.x = f2h2(fmaxf(a[0][2], 0.f), fmaxf(a[0][3], 0.f));
        w1.y = f2h2(fmaxf(a[1][2], 0.f), fmaxf(a[1][3], 0.f));
        w1.z = f2h2(fmaxf(a[2][2], 0.f), fmaxf(a[2][3], 0.f));
        w1.w = f2h2(fmaxf(a[3][2], 0.f), fmaxf(a[3][3], 0.f));
        *(uint4*)(Asw + (tc * 2) * 68 + tr * 4) = w0;       // ch pair {tc*4, tc*4+1}
        *(uint4*)(Asw + (tc * 2 + 1) * 68 + tr * 4) = w1;   // ch pair {tc*4+2, tc*4+3}
    }
    for (int i = t; i < C * C; i += 256) Ws[i] = W2[i];
    __syncthreads();

    // ---- GEMM2: z = relu(t1@W2+b2) ----
    float4 b2v = ((const float4*)b2)[tc];
#pragma unroll
    for (int i = 0; i < 4; ++i) { a[i][0] = b2v.x; a[i][1] = b2v.y; a[i][2] = b2v.z; a[i][3] = b2v.w; }
#pragma unroll 2
    for (int w = 0; w < 32; ++w) {
        uint4 aw = *(const uint4*)(Asw + w * 68 + tr * 4);
        float2 r0 = h2f(aw.x), r1 = h2f(aw.y), r2 = h2f(aw.z), r3 = h2f(aw.w);
        float4 w0 = *(const float4*)(Ws + (2 * w) * C + tc * 4);
        float4 w1 = *(const float4*)(Ws + (2 * w + 1) * C + tc * 4);
        float e0[4] = {r0.x, r1.x, r2.x, r3.x};
        float e1[4] = {r0.y, r1.y, r2.y, r3.y};
#pragma unroll
        for (int i = 0; i < 4; ++i) {
            a[i][0] = fmaf(e0[i], w0.x, a[i][0]); a[i][0] = fmaf(e1[i], w1.x, a[i][0]);
            a[i][1] = fmaf(e0[i], w0.y, a[i][1]); a[i][1] = fmaf(e1[i], w1.y, a[i][1]);
            a[i][2] = fmaf(e0[i], w0.z, a[i][2]); a[i][2] = fmaf(e1[i], w1.z, a[i][2]);
            a[i][3] = fmaf(e0[i], w0.w, a[i][3]); a[i][3] = fmaf(e1[i], w1.w, a[i][3]);
        }
    }

    // ---- relu, fp16 store, local BN stats (fp32) ----
    float lsum[4] = {0.f, 0.f, 0.f, 0.f};
    float lsq[4] = {0.f, 0.f, 0.f, 0.f};
#pragma unroll
    for (int i = 0; i < 4; ++i) {
        int grow = row0 + tr * 4 + i;
        if (grow < N_NODES) {
            float o0 = fmaxf(a[i][0], 0.f), o1 = fmaxf(a[i][1], 0.f);
            float o2 = fmaxf(a[i][2], 0.f), o3 = fmaxf(a[i][3], 0.f);
            uint2 o;
            o.x = f2h2(o0, o1);
            o.y = f2h2(o2, o3);
            ((uint2*)z_out)[grow * 16 + tc] = o;
            lsum[0] += o0; lsum[1] += o1; lsum[2] += o2; lsum[3] += o3;
            lsq[0] += o0 * o0; lsq[1] += o1 * o1; lsq[2] += o2 * o2; lsq[3] += o3 * o3;
        }
    }
    __syncthreads();  // Ws(W2) reads done; reuse as reduction buffer 16x128
    float* red = Ws;
#pragma unroll
    for (int j = 0; j < 4; ++j) {
        red[tr * 128 + tc * 4 + j] = lsum[j];
        red[tr * 128 + 64 + tc * 4 + j] = lsq[j];
    }
    __syncthreads();
    if (t < 128) {
        float s = 0.f;
#pragma unroll
        for (int r = 0; r < 16; ++r) s += red[r * 128 + t];
        atomicAdd(&stats_out[t], s);  // [0..63]=sum, [64..127]=sumsq
    }
}

// ---------------- pool: segmented reduction, in-kernel BN finalize ----------------
__global__ __launch_bounds__(256) void pool_kernel(const u32* __restrict__ z,
                                                   const float* __restrict__ stats,
                                                   const float* __restrict__ gamma,
                                                   const float* __restrict__ beta,
                                                   const int* __restrict__ goffs,
                                                   float* __restrict__ g) {
    __shared__ float4 red[256];
    int t = threadIdx.x;
    int tc = t & 15, tr = t >> 4;
    int gr = blockIdx.x;
    int beg = goffs[gr], end = goffs[gr + 1];
    const uint2* z2 = (const uint2*)z;
    float4 acc = make_float4(0.f, 0.f, 0.f, 0.f);
    for (int n = beg + tr; n < end; n += 16) {
        uint2 v = z2[n * 16 + tc];
        float2 a = h2f(v.x), c = h2f(v.y);
        acc.x += a.x; acc.y += a.y; acc.z += c.x; acc.w += c.y;
    }
    red[tr * 16 + tc] = acc;
    for (int s = 8; s > 0; s >>= 1) {
        __syncthreads();
        if (tr < s) {
            float4 o = red[(tr + s) * 16 + tc];
            float4 m = red[tr * 16 + tc];
            m.x += o.x; m.y += o.y; m.z += o.z; m.w += o.w;
            red[tr * 16 + tc] = m;
        }
    }
    __syncthreads();
    if (tr == 0) {
        float4 sum = red[tc];
        const float invN = 1.0f / (float)N_NODES;
        float scp[4], shp[4];
#pragma unroll
        for (int j = 0; j < 4; ++j) {
            int ch = tc * 4 + j;
            float mean = stats[ch] * invN;
            float var = stats[C + ch] * invN - mean * mean;
            float rstd = rsqrtf(var + BN_EPS);
            scp[j] = gamma[ch] * rstd;
            shp[j] = beta[ch] - mean * scp[j];
        }
        float cnt = (float)(end - beg);
        float4 o;
        o.x = fmaf(sum.x, scp[0], cnt * shp[0]);
        o.y = fmaf(sum.y, scp[1], cnt * shp[1]);
        o.z = fmaf(sum.z, scp[2], cnt * shp[2]);
        o.w = fmaf(sum.w, scp[3], cnt * shp[3]);
        ((float4*)g)[gr * 16 + tc] = o;
    }
}

// ---------------- head ----------------
__global__ __launch_bounds__(256) void head_kernel(const float* __restrict__ g,
                                                   const float* __restrict__ fc1W,
                                                   const float* __restrict__ fc1b,
                                                   const float* __restrict__ fc2W,
                                                   const float* __restrict__ fc2b,
                                                   float* __restrict__ out) {
    __shared__ float W1s[C * C];
    __shared__ float W2s[C * 16];
    __shared__ float gs[4][C], t1s[4][C];
    int t = threadIdx.x;
    for (int i = t; i < C * C; i += 256) W1s[i] = fc1W[i];
    for (int i = t; i < C * 16; i += 256) W2s[i] = fc2W[i];
    int ch = t & 63, rr = t >> 6;
    int g0 = blockIdx.x * 4;
    gs[rr][ch] = g[(g0 + rr) * C + ch];
    __syncthreads();
    float a1 = fc1b[ch];
#pragma unroll 8
    for (int k = 0; k < C; ++k) a1 = fmaf(gs[rr][k], W1s[k * C + ch], a1);
    t1s[rr][ch] = fmaxf(a1, 0.f);
    __syncthreads();
    if (t < 64) {
        int o = t & 15, r2 = t >> 4;
        float a2 = fc2b[o];
#pragma unroll 8
        for (int k = 0; k < C; ++k) a2 = fmaf(t1s[r2][k], W2s[k * 16 + o], a2);
        out[(g0 + r2) * 16 + o] = a2;
    }
}

extern "C" void kernel_launch(void* const* d_in, const int* in_sizes, int n_in,
                              void* d_out, int out_size, void* d_ws, size_t ws_size,
                              hipStream_t stream) {
    const float* x    = (const float*)d_in[0];
    const int*   ei   = (const int*)d_in[1];
    const int*   batch= (const int*)d_in[2];
    const float* encW = (const float*)d_in[3];
    const float* encb = (const float*)d_in[4];
    const float* cW1  = (const float*)d_in[5];
    const float* cb1  = (const float*)d_in[6];
    const float* cW2  = (const float*)d_in[7];
    const float* cb2  = (const float*)d_in[8];
    const float* gam  = (const float*)d_in[9];
    const float* bet  = (const float*)d_in[10];
    const float* f1W  = (const float*)d_in[11];
    const float* f1b  = (const float*)d_in[12];
    const float* f2W  = (const float*)d_in[13];
    const float* f2b  = (const float*)d_in[14];
    float* out = (float*)d_out;

    char* ws = (char*)d_ws;
    u32*   zA      = (u32*)  (ws);                    // fp16: 6.4 MB
    u32*   zB      = (u32*)  (ws + 6400000);          // fp16: 6.4 MB
    u16*   csr     = (u16*)  (ws + 12800000);         // NBUCK*BCAP*2 = 2,007,040 B
    u32*   staged  = (u32*)  (ws + 14807040);         // NBUCK*BCAP*4 = 4,014,080 B
    int*   offs    = (int*)  (ws + 18821120);         // 50000 ints
    int*   ends    = (int*)  (ws + 19021120);         // 50000 ints
    int*   bcursor = (int*)  (ws + 19221120);         // 196 ints
    float* stats   = (float*)(ws + 19222016);         // 5*128 floats
    int*   goffs   = (int*)  (ws + 19224576);         // 513 ints
    float* gpool   = (float*)(ws + 19226752);         // 128 KB

    // --- single-pass bucketed CSR build + graph offsets ---
    hipMemsetAsync(stats, 0, 5 * 2 * C * sizeof(float), stream);
    seed_kernel<<<1, 256, 0, stream>>>(bcursor);
    csr_stage<<<NBUCK, 256, 0, stream>>>(ei, bcursor, staged);
    csr_finalize<<<NBUCK, 256, 0, stream>>>(staged, bcursor, csr, offs, ends);
    gstart_kernel<<<SCAN_BLOCKS, 256, 0, stream>>>(batch, goffs);

    enc_kernel<<<(N_NODES + 127) / 128, 256, 0, stream>>>(x, encW, encb, zA);

    u32* zin = zA;
    u32* zout = zB;
    for (int l = 0; l < N_LAYERS; ++l) {
        const float* st_prev = stats + (size_t)(l > 0 ? l - 1 : 0) * 2 * C;
        const float* gm_prev = gam + (size_t)(l > 0 ? l - 1 : 0) * C;
        const float* bt_prev = bet + (size_t)(l > 0 ? l - 1 : 0) * C;
        mlp_gather_kernel<<<(N_NODES + 63) / 64, 256, 0, stream>>>(
            csr, offs, ends, zin, st_prev, gm_prev, bt_prev, l > 0 ? 1 : 0, zout,
            cW1 + (size_t)l * C * C, cb1 + (size_t)l * C,
            cW2 + (size_t)l * C * C, cb2 + (size_t)l * C,
            stats + (size_t)l * 2 * C);
        u32* tmp = zin; zin = zout; zout = tmp;
    }

    // zin holds layer-5 pre-BN output; pool applies final BN (in-kernel finalize)
    pool_kernel<<<N_GRAPHS, 256, 0, stream>>>(zin,
                                              stats + (size_t)(N_LAYERS - 1) * 2 * C,
                                              gam + (size_t)(N_LAYERS - 1) * C,
                                              bet + (size_t)(N_LAYERS - 1) * C,
                                              goffs, gpool);
    head_kernel<<<N_GRAPHS / 4, 256, 0, stream>>>(gpool, f1W, f1b, f2W, f2b, out);
}